// Round 1
// baseline (140.441 us; speedup 1.0000x reference)
//
#include <hip/hip_runtime.h>
#include <math.h>

#define NB   8
#define SEQ  2048
#define EMB  8
#define NH   4
#define NFF  2048
#define NTOK (NB*SEQ)          // 16384
#define LNEPS 1e-5f

__device__ __forceinline__ float dot8(const float4& a, const float4& b,
                                      const float4& c, const float4& d) {
    return a.x*b.x + a.y*b.y + a.z*b.z + a.w*b.w
         + c.x*d.x + c.y*d.y + c.z*d.z + c.w*d.w;
}

// ---------------------------------------------------------------------------
// proj = x @ Wp^T  (per token), and W2T[f][e] = W2[e][f]
// ---------------------------------------------------------------------------
__global__ __launch_bounds__(256) void k_prep(const float* __restrict__ x,
                                              const float* __restrict__ Wp,
                                              const float* __restrict__ W2,
                                              float* __restrict__ proj,
                                              float* __restrict__ w2t) {
    int t = blockIdx.x * 256 + threadIdx.x;
    if (t < NTOK) {
        const float4* xr = (const float4*)(x + (size_t)t * EMB);
        float4 xa = xr[0], xb = xr[1];
        float o[8];
#pragma unroll
        for (int e = 0; e < 8; ++e) {
            const float4* wr = (const float4*)(Wp + e * EMB);
            o[e] = dot8(xa, wr[0], xb, wr[1]);
        }
        float4* pr = (float4*)(proj + (size_t)t * EMB);
        pr[0] = make_float4(o[0], o[1], o[2], o[3]);
        pr[1] = make_float4(o[4], o[5], o[6], o[7]);
    }
    if (t < NFF) {
        float o[8];
#pragma unroll
        for (int e = 0; e < 8; ++e) o[e] = W2[e * NFF + t];
        float4* wr = (float4*)(w2t + (size_t)t * EMB);
        wr[0] = make_float4(o[0], o[1], o[2], o[3]);
        wr[1] = make_float4(o[4], o[5], o[6], o[7]);
    }
}

// ---------------------------------------------------------------------------
// attention for one (b,h): q=k=v = proj[:, 2h:2h+2].  No-max softmax
// (scores bounded, fp32-safe) so key-split partials combine linearly.
// Block: 256 threads = 4 key-subranges x 64 queries.  K staged in LDS (16KB).
// ---------------------------------------------------------------------------
#define QC 64
__global__ __launch_bounds__(256) void k_attn(const float* __restrict__ proj,
                                              float* __restrict__ ctx) {
    __shared__ float2 Ks[SEQ];              // 16 KB
    __shared__ float red[3][4][QC];         // l, a0, a1 partials

    int bid = blockIdx.x;
    int qc  = bid & (SEQ / QC - 1);         // 32 query chunks
    int bh  = bid >> 5;
    int b   = bh >> 2;
    int h   = bh & 3;

    const float* base = proj + (size_t)b * SEQ * EMB + 2 * h;
    for (int j = threadIdx.x; j < SEQ; j += 256)
        Ks[j] = *(const float2*)(base + (size_t)j * EMB);
    __syncthreads();

    int ql  = threadIdx.x & 63;
    int sub = threadIdx.x >> 6;             // wave-uniform
    int qi  = qc * QC + ql;

    float2 q = Ks[qi];
    const float SC = 0.70710678118654752f;  // 1/sqrt(DK)
    float qs0 = q.x * SC, qs1 = q.y * SC;

    float l = 0.f, a0 = 0.f, a1 = 0.f;
    int j0 = sub * (SEQ / 4);
#pragma unroll 4
    for (int jj = 0; jj < SEQ / 4; ++jj) {
        float2 k = Ks[j0 + jj];             // same addr across lanes: broadcast
        float s = qs0 * k.x + qs1 * k.y;
        float p = __expf(s);
        l += p;
        a0 = fmaf(p, k.x, a0);
        a1 = fmaf(p, k.y, a1);
    }
    red[0][sub][ql] = l;
    red[1][sub][ql] = a0;
    red[2][sub][ql] = a1;
    __syncthreads();

    if (sub == 0) {
        l  = red[0][0][ql] + red[0][1][ql] + red[0][2][ql] + red[0][3][ql];
        a0 = red[1][0][ql] + red[1][1][ql] + red[1][2][ql] + red[1][3][ql];
        a1 = red[2][0][ql] + red[2][1][ql] + red[2][2][ql] + red[2][3][ql];
        float inv = 1.0f / l;
        *(float2*)(ctx + ((size_t)b * SEQ + qi) * EMB + 2 * h) =
            make_float2(a0 * inv, a1 * inv);
    }
}

// ---------------------------------------------------------------------------
// attn_out = ctx @ Wo^T ; x1 = LN1(x + attn_out) ; outq = cumprod(cos(x1))
// ---------------------------------------------------------------------------
__global__ __launch_bounds__(256) void k_post(const float* __restrict__ ctx,
                                              const float* __restrict__ x,
                                              const float* __restrict__ Wo,
                                              const float* __restrict__ g1,
                                              const float* __restrict__ b1,
                                              float* __restrict__ x1,
                                              float* __restrict__ outq) {
    int t = blockIdx.x * 256 + threadIdx.x;
    if (t >= NTOK) return;

    const float4* cr = (const float4*)(ctx + (size_t)t * EMB);
    float4 ca = cr[0], cb = cr[1];
    const float4* xr = (const float4*)(x + (size_t)t * EMB);
    float4 xa = xr[0], xb = xr[1];
    const float* xs = (const float*)&xa;    // xs[0..3], then xb

    float y[8], s = 0.f;
#pragma unroll
    for (int e = 0; e < 8; ++e) {
        const float4* wr = (const float4*)(Wo + e * EMB);
        float ao = dot8(ca, wr[0], cb, wr[1]);
        float xv = (e < 4) ? ((const float*)&xa)[e] : ((const float*)&xb)[e - 4];
        y[e] = xv + ao;
        s += y[e];
    }
    (void)xs;
    float mu = s * 0.125f, vs = 0.f;
#pragma unroll
    for (int e = 0; e < 8; ++e) { float d = y[e] - mu; vs += d * d; }
    float r = rsqrtf(vs * 0.125f + LNEPS);

    float xo[8], qo[8], cp = 1.f;
#pragma unroll
    for (int e = 0; e < 8; ++e) {
        float v = (y[e] - mu) * r * g1[e] + b1[e];
        xo[e] = v;
        cp *= __cosf(v);
        qo[e] = cp;
    }
    float4* x1r = (float4*)(x1 + (size_t)t * EMB);
    x1r[0] = make_float4(xo[0], xo[1], xo[2], xo[3]);
    x1r[1] = make_float4(xo[4], xo[5], xo[6], xo[7]);
    float4* qr = (float4*)(outq + (size_t)t * EMB);
    qr[0] = make_float4(qo[0], qo[1], qo[2], qo[3]);
    qr[1] = make_float4(qo[4], qo[5], qo[6], qo[7]);
}

// ---------------------------------------------------------------------------
// h = relu(outq @ W1^T + bb1); ffn = h @ W2^T + bb2; out = LN2(x1 + ffn)
// Block: 256 threads = 4 f-subranges (512 each) x 64 tokens; LDS reduce.
// ---------------------------------------------------------------------------
__global__ __launch_bounds__(256) void k_ffn(const float* __restrict__ outq,
                                             const float* __restrict__ x1,
                                             const float* __restrict__ W1,
                                             const float* __restrict__ bb1,
                                             const float* __restrict__ w2t,
                                             const float* __restrict__ bb2,
                                             const float* __restrict__ g2,
                                             const float* __restrict__ b2,
                                             float* __restrict__ out) {
    __shared__ float red[4][64][8];         // 8 KB

    int tl  = threadIdx.x & 63;
    int sub = threadIdx.x >> 6;             // wave-uniform
    int tok = blockIdx.x * 64 + tl;

    const float4* qr = (const float4*)(outq + (size_t)tok * EMB);
    float4 qa = qr[0], qb = qr[1];

    float acc[8] = {0, 0, 0, 0, 0, 0, 0, 0};
    int f0 = sub * (NFF / 4);
    for (int i = 0; i < NFF / 4; ++i) {
        int f = f0 + i;
        const float4* w1r = (const float4*)(W1 + (size_t)f * EMB);
        float4 wa = w1r[0], wb = w1r[1];
        float hv = fmaxf(dot8(qa, wa, qb, wb) + bb1[f], 0.f);
        const float4* w2r = (const float4*)(w2t + (size_t)f * EMB);
        float4 va = w2r[0], vb = w2r[1];
        acc[0] = fmaf(hv, va.x, acc[0]);
        acc[1] = fmaf(hv, va.y, acc[1]);
        acc[2] = fmaf(hv, va.z, acc[2]);
        acc[3] = fmaf(hv, va.w, acc[3]);
        acc[4] = fmaf(hv, vb.x, acc[4]);
        acc[5] = fmaf(hv, vb.y, acc[5]);
        acc[6] = fmaf(hv, vb.z, acc[6]);
        acc[7] = fmaf(hv, vb.w, acc[7]);
    }
#pragma unroll
    for (int e = 0; e < 8; ++e) red[sub][tl][e] = acc[e];
    __syncthreads();

    if (sub == 0) {
        const float* x1r = x1 + (size_t)tok * EMB;
        float y[8], s = 0.f;
#pragma unroll
        for (int e = 0; e < 8; ++e) {
            float v = red[0][tl][e] + red[1][tl][e] + red[2][tl][e] + red[3][tl][e];
            v += bb2[e] + x1r[e];
            y[e] = v;
            s += v;
        }
        float mu = s * 0.125f, vs = 0.f;
#pragma unroll
        for (int e = 0; e < 8; ++e) { float d = y[e] - mu; vs += d * d; }
        float r = rsqrtf(vs * 0.125f + LNEPS);
        float o[8];
#pragma unroll
        for (int e = 0; e < 8; ++e) o[e] = (y[e] - mu) * r * g2[e] + b2[e];
        float4* orow = (float4*)(out + (size_t)tok * EMB);
        orow[0] = make_float4(o[0], o[1], o[2], o[3]);
        orow[1] = make_float4(o[4], o[5], o[6], o[7]);
    }
}

// ---------------------------------------------------------------------------
extern "C" void kernel_launch(void* const* d_in, const int* in_sizes, int n_in,
                              void* d_out, int out_size, void* d_ws, size_t ws_size,
                              hipStream_t stream) {
    const float* x   = (const float*)d_in[0];
    const float* Wp  = (const float*)d_in[1];
    const float* Wo  = (const float*)d_in[2];
    const float* g1  = (const float*)d_in[3];
    const float* b1  = (const float*)d_in[4];
    const float* W1  = (const float*)d_in[5];
    const float* bb1 = (const float*)d_in[6];
    const float* W2  = (const float*)d_in[7];
    const float* bb2 = (const float*)d_in[8];
    const float* g2  = (const float*)d_in[9];
    const float* b2  = (const float*)d_in[10];
    float* out = (float*)d_out;

    float* ws   = (float*)d_ws;
    float* proj = ws;                 // 131072 f32
    float* ctx  = ws + 131072;        // 131072 f32
    float* x1   = ws + 262144;        // 131072 f32
    float* outq = ws + 393216;        // 131072 f32
    float* w2t  = ws + 524288;        // 16384 f32

    hipLaunchKernelGGL(k_prep, dim3(NTOK / 256), dim3(256), 0, stream,
                       x, Wp, W2, proj, w2t);
    hipLaunchKernelGGL(k_attn, dim3(NB * NH * (SEQ / QC)), dim3(256), 0, stream,
                       proj, ctx);
    hipLaunchKernelGGL(k_post, dim3(NTOK / 256), dim3(256), 0, stream,
                       ctx, x, Wo, g1, b1, x1, outq);
    hipLaunchKernelGGL(k_ffn, dim3(NTOK / 64), dim3(256), 0, stream,
                       outq, x1, W1, bb1, w2t, bb2, g2, b2, out);
}

// Round 2
// 74.165 us; speedup vs baseline: 1.8936x; 1.8936x over previous
//
#include <hip/hip_runtime.h>
#include <math.h>

#define NB   8
#define SEQ  2048
#define EMB  8
#define NH   4
#define NFF  2048
#define NTOK (NB*SEQ)          // 16384
#define LNEPS 1e-5f

__device__ __forceinline__ float dot8(const float4& a, const float4& b,
                                      const float4& c, const float4& d) {
    return a.x*b.x + a.y*b.y + a.z*b.z + a.w*b.w
         + c.x*d.x + c.y*d.y + c.z*d.z + c.w*d.w;
}

// ---------------------------------------------------------------------------
// proj = x @ Wp^T  (per token), and W2T[f][e] = W2[e][f]
// ---------------------------------------------------------------------------
__global__ __launch_bounds__(256) void k_prep(const float* __restrict__ x,
                                              const float* __restrict__ Wp,
                                              const float* __restrict__ W2,
                                              float* __restrict__ proj,
                                              float* __restrict__ w2t) {
    int t = blockIdx.x * 256 + threadIdx.x;
    if (t < NTOK) {
        const float4* xr = (const float4*)(x + (size_t)t * EMB);
        float4 xa = xr[0], xb = xr[1];
        float o[8];
#pragma unroll
        for (int e = 0; e < 8; ++e) {
            const float4* wr = (const float4*)(Wp + e * EMB);
            o[e] = dot8(xa, wr[0], xb, wr[1]);
        }
        float4* pr = (float4*)(proj + (size_t)t * EMB);
        pr[0] = make_float4(o[0], o[1], o[2], o[3]);
        pr[1] = make_float4(o[4], o[5], o[6], o[7]);
    }
    if (t < NFF) {
        float o[8];
#pragma unroll
        for (int e = 0; e < 8; ++e) o[e] = W2[e * NFF + t];
        float4* wr = (float4*)(w2t + (size_t)t * EMB);
        wr[0] = make_float4(o[0], o[1], o[2], o[3]);
        wr[1] = make_float4(o[4], o[5], o[6], o[7]);
    }
}

// ---------------------------------------------------------------------------
// attention for one (b,h): q=k=v = proj[:, 2h:2h+2].  No-max softmax
// (scores bounded, fp32-safe) so key-split partials combine linearly.
// Block: 256 threads = 4 key-subranges x 64 queries.  K staged in LDS (16KB).
// ---------------------------------------------------------------------------
#define QC 64
__global__ __launch_bounds__(256) void k_attn(const float* __restrict__ proj,
                                              float* __restrict__ ctx) {
    __shared__ float2 Ks[SEQ];              // 16 KB
    __shared__ float red[3][4][QC];         // l, a0, a1 partials

    int bid = blockIdx.x;
    int qc  = bid & (SEQ / QC - 1);         // 32 query chunks
    int bh  = bid >> 5;
    int b   = bh >> 2;
    int h   = bh & 3;

    const float* base = proj + (size_t)b * SEQ * EMB + 2 * h;
    for (int j = threadIdx.x; j < SEQ; j += 256)
        Ks[j] = *(const float2*)(base + (size_t)j * EMB);
    __syncthreads();

    int ql  = threadIdx.x & 63;
    int sub = threadIdx.x >> 6;             // wave-uniform
    int qi  = qc * QC + ql;

    float2 q = Ks[qi];
    const float SC = 0.70710678118654752f;  // 1/sqrt(DK)
    float qs0 = q.x * SC, qs1 = q.y * SC;

    float l = 0.f, a0 = 0.f, a1 = 0.f;
    int j0 = sub * (SEQ / 4);
#pragma unroll 4
    for (int jj = 0; jj < SEQ / 4; ++jj) {
        float2 k = Ks[j0 + jj];             // same addr across lanes: broadcast
        float s = qs0 * k.x + qs1 * k.y;
        float p = __expf(s);
        l += p;
        a0 = fmaf(p, k.x, a0);
        a1 = fmaf(p, k.y, a1);
    }
    red[0][sub][ql] = l;
    red[1][sub][ql] = a0;
    red[2][sub][ql] = a1;
    __syncthreads();

    if (sub == 0) {
        l  = red[0][0][ql] + red[0][1][ql] + red[0][2][ql] + red[0][3][ql];
        a0 = red[1][0][ql] + red[1][1][ql] + red[1][2][ql] + red[1][3][ql];
        a1 = red[2][0][ql] + red[2][1][ql] + red[2][2][ql] + red[2][3][ql];
        float inv = 1.0f / l;
        *(float2*)(ctx + ((size_t)b * SEQ + qi) * EMB + 2 * h) =
            make_float2(a0 * inv, a1 * inv);
    }
}

// ---------------------------------------------------------------------------
// attn_out = ctx @ Wo^T ; x1 = LN1(x + attn_out) ; outq = cumprod(cos(x1))
// ---------------------------------------------------------------------------
__global__ __launch_bounds__(256) void k_post(const float* __restrict__ ctx,
                                              const float* __restrict__ x,
                                              const float* __restrict__ Wo,
                                              const float* __restrict__ g1,
                                              const float* __restrict__ b1,
                                              float* __restrict__ x1,
                                              float* __restrict__ outq) {
    int t = blockIdx.x * 256 + threadIdx.x;
    if (t >= NTOK) return;

    const float4* cr = (const float4*)(ctx + (size_t)t * EMB);
    float4 ca = cr[0], cb = cr[1];
    const float4* xr = (const float4*)(x + (size_t)t * EMB);
    float4 xa = xr[0], xb = xr[1];

    float y[8], s = 0.f;
#pragma unroll
    for (int e = 0; e < 8; ++e) {
        const float4* wr = (const float4*)(Wo + e * EMB);
        float ao = dot8(ca, wr[0], cb, wr[1]);
        float xv = (e < 4) ? ((const float*)&xa)[e] : ((const float*)&xb)[e - 4];
        y[e] = xv + ao;
        s += y[e];
    }
    float mu = s * 0.125f, vs = 0.f;
#pragma unroll
    for (int e = 0; e < 8; ++e) { float d = y[e] - mu; vs += d * d; }
    float r = rsqrtf(vs * 0.125f + LNEPS);

    float xo[8], qo[8], cp = 1.f;
#pragma unroll
    for (int e = 0; e < 8; ++e) {
        float v = (y[e] - mu) * r * g1[e] + b1[e];
        xo[e] = v;
        cp *= __cosf(v);
        qo[e] = cp;
    }
    float4* x1r = (float4*)(x1 + (size_t)t * EMB);
    x1r[0] = make_float4(xo[0], xo[1], xo[2], xo[3]);
    x1r[1] = make_float4(xo[4], xo[5], xo[6], xo[7]);
    float4* qr = (float4*)(outq + (size_t)t * EMB);
    qr[0] = make_float4(qo[0], qo[1], qo[2], qo[3]);
    qr[1] = make_float4(qo[4], qo[5], qo[6], qo[7]);
}

// ---------------------------------------------------------------------------
// h = relu(outq @ W1^T + bb1); ffn = h @ W2^T + bb2; out = LN2(x1 + ffn)
// v2: 32 tokens/block (grid=512, 8 waves/CU), thread = (tg: 4 tokens) x
// (sub: 64-wide f-chunk).  One W-row pair load feeds 4 tokens (~68 FMA) for
// ILP.  LDS reduce over 32 subranges, LN2 via 8-lane shuffles.
// ---------------------------------------------------------------------------
#define TB   32                 // tokens per block
#define NSUB 32                 // f subranges
#define FCH  (NFF / NSUB)       // 64 f per thread
__global__ __launch_bounds__(256) void k_ffn(const float* __restrict__ outq,
                                             const float* __restrict__ x1,
                                             const float* __restrict__ W1,
                                             const float* __restrict__ bb1,
                                             const float* __restrict__ w2t,
                                             const float* __restrict__ bb2,
                                             const float* __restrict__ g2,
                                             const float* __restrict__ b2,
                                             float* __restrict__ out) {
    __shared__ float red[NSUB][TB + 1][8];  // +1 row pad: partial-write conflicts <=2-way

    int tg   = threadIdx.x & 7;             // 8 token groups x 4 tokens
    int sub  = threadIdx.x >> 3;            // 32 f-subranges
    int tok0 = blockIdx.x * TB + tg * 4;

    float4 qa[4], qb[4];
#pragma unroll
    for (int k = 0; k < 4; ++k) {
        const float4* qr = (const float4*)(outq + (size_t)(tok0 + k) * EMB);
        qa[k] = qr[0];
        qb[k] = qr[1];
    }

    float acc[4][8];
#pragma unroll
    for (int k = 0; k < 4; ++k)
#pragma unroll
        for (int e = 0; e < 8; ++e) acc[k][e] = 0.f;

    int f0 = sub * FCH;
#pragma unroll 2
    for (int i = 0; i < FCH; ++i) {
        int f = f0 + i;
        const float4* w1r = (const float4*)(W1 + (size_t)f * EMB);
        float4 wa = w1r[0], wb = w1r[1];
        float bias = bb1[f];
        const float4* w2r = (const float4*)(w2t + (size_t)f * EMB);
        float4 va = w2r[0], vb = w2r[1];
#pragma unroll
        for (int k = 0; k < 4; ++k) {
            float hv = fmaxf(dot8(qa[k], wa, qb[k], wb) + bias, 0.f);
            acc[k][0] = fmaf(hv, va.x, acc[k][0]);
            acc[k][1] = fmaf(hv, va.y, acc[k][1]);
            acc[k][2] = fmaf(hv, va.z, acc[k][2]);
            acc[k][3] = fmaf(hv, va.w, acc[k][3]);
            acc[k][4] = fmaf(hv, vb.x, acc[k][4]);
            acc[k][5] = fmaf(hv, vb.y, acc[k][5]);
            acc[k][6] = fmaf(hv, vb.z, acc[k][6]);
            acc[k][7] = fmaf(hv, vb.w, acc[k][7]);
        }
    }
#pragma unroll
    for (int k = 0; k < 4; ++k) {
        float4* dst = (float4*)&red[sub][tg * 4 + k][0];
        dst[0] = make_float4(acc[k][0], acc[k][1], acc[k][2], acc[k][3]);
        dst[1] = make_float4(acc[k][4], acc[k][5], acc[k][6], acc[k][7]);
    }
    __syncthreads();

    // reduce over subranges: thread = (rtok: 32) x (re: 8)
    int rtok = threadIdx.x >> 3;
    int re   = threadIdx.x & 7;
    float v = 0.f;
#pragma unroll
    for (int s = 0; s < NSUB; ++s) v += red[s][rtok][re];
    int tok = blockIdx.x * TB + rtok;
    v += bb2[re] + x1[(size_t)tok * EMB + re];

    // LN2 across the 8 lanes of this token (e = low 3 bits of lane id)
    float s8 = v;
    s8 += __shfl_xor(s8, 1);
    s8 += __shfl_xor(s8, 2);
    s8 += __shfl_xor(s8, 4);
    float mu = s8 * 0.125f;
    float d  = v - mu;
    float vs = d * d;
    vs += __shfl_xor(vs, 1);
    vs += __shfl_xor(vs, 2);
    vs += __shfl_xor(vs, 4);
    float r = rsqrtf(vs * 0.125f + LNEPS);
    out[(size_t)tok * EMB + re] = d * r * g2[re] + b2[re];
}

// ---------------------------------------------------------------------------
extern "C" void kernel_launch(void* const* d_in, const int* in_sizes, int n_in,
                              void* d_out, int out_size, void* d_ws, size_t ws_size,
                              hipStream_t stream) {
    const float* x   = (const float*)d_in[0];
    const float* Wp  = (const float*)d_in[1];
    const float* Wo  = (const float*)d_in[2];
    const float* g1  = (const float*)d_in[3];
    const float* b1  = (const float*)d_in[4];
    const float* W1  = (const float*)d_in[5];
    const float* bb1 = (const float*)d_in[6];
    const float* W2  = (const float*)d_in[7];
    const float* bb2 = (const float*)d_in[8];
    const float* g2  = (const float*)d_in[9];
    const float* b2  = (const float*)d_in[10];
    float* out = (float*)d_out;

    float* ws   = (float*)d_ws;
    float* proj = ws;                 // 131072 f32
    float* ctx  = ws + 131072;        // 131072 f32
    float* x1   = ws + 262144;        // 131072 f32
    float* outq = ws + 393216;        // 131072 f32
    float* w2t  = ws + 524288;        // 16384 f32

    hipLaunchKernelGGL(k_prep, dim3(NTOK / 256), dim3(256), 0, stream,
                       x, Wp, W2, proj, w2t);
    hipLaunchKernelGGL(k_attn, dim3(NB * NH * (SEQ / QC)), dim3(256), 0, stream,
                       proj, ctx);
    hipLaunchKernelGGL(k_post, dim3(NTOK / 256), dim3(256), 0, stream,
                       ctx, x, Wo, g1, b1, x1, outq);
    hipLaunchKernelGGL(k_ffn, dim3(NTOK / TB), dim3(256), 0, stream,
                       outq, x1, W1, bb1, w2t, bb2, g2, b2, out);
}